// Round 1
// baseline (526.903 us; speedup 1.0000x reference)
//
#include <hip/hip_runtime.h>
#include <hip/hip_bf16.h>
#include <stdint.h>

typedef __attribute__((ext_vector_type(8))) short short8;   // 8 bf16 = 4 VGPRs
typedef __attribute__((ext_vector_type(4))) float f32x4;    // MFMA C/D frag

typedef __attribute__((address_space(3))) uint8_t lds_u8;
typedef __attribute__((address_space(1))) uint8_t glb_u8;

__device__ __forceinline__ void load_lds_16(const void* g, void* l) {
    __builtin_amdgcn_global_load_lds((glb_u8*)g, (lds_u8*)l, 16, 0, 0);
}

__device__ __forceinline__ unsigned short f2b(float f) {
    __hip_bfloat16 h = __float2bfloat16(f);
    return __builtin_bit_cast(unsigned short, h);
}

constexpr int Bz = 32, Ss = 577, Dd = 768, Hh = 12;
constexpr int Mm = Bz * Ss;          // 18464
constexpr int QKV_N = 3 * Dd;        // 2304
constexpr float SCALE_L2E = 0.125f * 1.4426950408889634f;

// ---------------- cast x -> bf16 ----------------
__global__ void cast_f32_bf16(const float* __restrict__ src,
                              unsigned short* __restrict__ dst, int n4) {
    int i = blockIdx.x * blockDim.x + threadIdx.x;
    if (i >= n4) return;
    float4 v = ((const float4*)src)[i];
    ushort4 o;
    o.x = f2b(v.x); o.y = f2b(v.y); o.z = f2b(v.z); o.w = f2b(v.w);
    ((ushort4*)dst)[i] = o;
}

// ---------------- transpose + cast: src fp32 [R][C] -> dst bf16 [C][R] ----------------
__global__ void transpose_cast(const float* __restrict__ src,
                               unsigned short* __restrict__ dst, int R, int C) {
    __shared__ unsigned short tile[32][33];
    int c0 = blockIdx.x * 32, r0 = blockIdx.y * 32;
    int tx = threadIdx.x, ty = threadIdx.y;  // (32,8)
#pragma unroll
    for (int i = 0; i < 4; ++i)
        tile[ty + i * 8][tx] = f2b(src[(size_t)(r0 + ty + i * 8) * C + c0 + tx]);
    __syncthreads();
#pragma unroll
    for (int i = 0; i < 4; ++i) {
        int rr = ty + i * 8;
        dst[(size_t)(c0 + rr) * R + r0 + tx] = tile[tx][rr];
    }
}

// ---------------- TN GEMM: C[M][N] = A[M][768] * Bt[N][768]^T + bias ----------------
// 128x128 tile, BK=32, 4 waves, 16x16x32 bf16 MFMA, global_load_lds staging,
// XOR-swizzled LDS chunk layout (2-way bank conflicts only == free).
template <int N_, bool OUT_BF16>
__global__ __launch_bounds__(256)
void gemm_tn(const unsigned short* __restrict__ A,
             const unsigned short* __restrict__ Bt,
             const float* __restrict__ bias,
             void* __restrict__ Cout) {
    constexpr int K = 768;
    __shared__ unsigned short Asm[128 * 32];
    __shared__ unsigned short Bsm[128 * 32];

    const int tid = threadIdx.x;
    const int wave = tid >> 6, lane = tid & 63;
    const int quad = lane >> 4, lc = lane & 15;
    const int wm = wave >> 1, wn = wave & 1;
    const int tm = blockIdx.x * 128;
    const int tn = blockIdx.y * 128;

    const int l4 = lane >> 2;          // 0..15 : row within 16-row staging slab
    const int cs = lane & 3;           // LDS chunk slot
    const int cx = cs ^ (l4 & 3);      // swizzled global chunk to fetch

    f32x4 acc[4][4] = {};

    for (int kb = 0; kb < K / 32; ++kb) {
        __syncthreads();
#pragma unroll
        for (int i = 0; i < 2; ++i) {
            int lrow = wave * 32 + i * 16 + l4;
            int arow = tm + lrow; if (arow >= Mm) arow = Mm - 1;
            const unsigned short* ga = A + (size_t)arow * K + kb * 32 + cx * 8;
            load_lds_16(ga, (void*)(Asm + (wave * 32 + i * 16) * 32));
            int brow = tn + lrow;
            const unsigned short* gb = Bt + (size_t)brow * K + kb * 32 + cx * 8;
            load_lds_16(gb, (void*)(Bsm + (wave * 32 + i * 16) * 32));
        }
        __syncthreads();

        short8 af[4], bf[4];
#pragma unroll
        for (int i = 0; i < 4; ++i) {
            int row = wm * 64 + i * 16 + lc;
            int c = quad ^ (row & 3);
            af[i] = *(const short8*)(Asm + row * 32 + c * 8);
            int brow = wn * 64 + i * 16 + lc;
            int cb = quad ^ (brow & 3);
            bf[i] = *(const short8*)(Bsm + brow * 32 + cb * 8);
        }
#pragma unroll
        for (int i = 0; i < 4; ++i)
#pragma unroll
            for (int j = 0; j < 4; ++j)
                acc[i][j] = __builtin_amdgcn_mfma_f32_16x16x32_bf16(af[i], bf[j], acc[i][j], 0, 0, 0);
    }

#pragma unroll
    for (int j = 0; j < 4; ++j) {
        int col = tn + wn * 64 + j * 16 + lc;
        float bv = bias[col];
#pragma unroll
        for (int i = 0; i < 4; ++i) {
#pragma unroll
            for (int r = 0; r < 4; ++r) {
                int row = tm + wm * 64 + i * 16 + quad * 4 + r;
                if (row < Mm) {
                    float v = acc[i][j][r] + bv;
                    if constexpr (OUT_BF16)
                        ((unsigned short*)Cout)[(size_t)row * N_ + col] = f2b(v);
                    else
                        ((float*)Cout)[(size_t)row * N_ + col] = v;
                }
            }
        }
    }
}

// ---------------- flash attention ----------------
// grid (10, 12, 32) = (qtile, head, batch); 256 threads = 4 waves x 16 queries.
__global__ __launch_bounds__(256)
void attn_kernel(const unsigned short* __restrict__ qkv,   // [Mm][2304] bf16
                 unsigned short* __restrict__ outb) {      // [Mm][768] bf16
    __shared__ unsigned short Vt[64 * 80];      // [dh][key], pad 80 keeps 16B align
    __shared__ unsigned short Pl[4][16 * 80];   // per-wave P [query][key]

    const int tid = threadIdx.x;
    const int wave = tid >> 6, lane = tid & 63;
    const int quad = lane >> 4, lc = lane & 15;
    const int qt = blockIdx.x, h = blockIdx.y, b = blockIdx.z;

    const int qbase = qt * 64 + wave * 16;
    int qrow = qbase + lc; if (qrow > Ss - 1) qrow = Ss - 1;
    const unsigned short* qp = qkv + (size_t)(b * Ss + qrow) * QKV_N + h * 64;

    short8 qf0 = *(const short8*)(qp + quad * 8);
    short8 qf1 = *(const short8*)(qp + 32 + quad * 8);

    float mrun[4], lrun[4];
    f32x4 oacc[4] = {};
#pragma unroll
    for (int r = 0; r < 4; ++r) { mrun[r] = -1e30f; lrun[r] = 0.f; }

    for (int kb = 0; kb < 10; ++kb) {
        const int kbase = kb * 64;
        __syncthreads();  // prev iter's Vt/Pl reads done before overwrite

        // stage V tile transposed: lane = key, wave = 16-dh slab
        {
            int key = kbase + lane; if (key > Ss - 1) key = Ss - 1;
            const unsigned short* vp =
                qkv + (size_t)(b * Ss + key) * QKV_N + 1536 + h * 64 + wave * 16;
            short8 v0 = *(const short8*)vp;
            short8 v1 = *(const short8*)(vp + 8);
#pragma unroll
            for (int j = 0; j < 8; ++j) {
                Vt[(wave * 16 + j) * 80 + lane]     = (unsigned short)v0[j];
                Vt[(wave * 16 + 8 + j) * 80 + lane] = (unsigned short)v1[j];
            }
        }

        // scores: S = Q K^T, K B-frags straight from global (16B/lane)
        f32x4 sfr[4];
#pragma unroll
        for (int f = 0; f < 4; ++f) {
            int key = kbase + f * 16 + lc;
            int keyc = key > Ss - 1 ? Ss - 1 : key;
            const unsigned short* kp =
                qkv + (size_t)(b * Ss + keyc) * QKV_N + 768 + h * 64;
            short8 k0 = *(const short8*)(kp + quad * 8);
            short8 k1 = *(const short8*)(kp + 32 + quad * 8);
            f32x4 z = {};
            z = __builtin_amdgcn_mfma_f32_16x16x32_bf16(qf0, k0, z, 0, 0, 0);
            z = __builtin_amdgcn_mfma_f32_16x16x32_bf16(qf1, k1, z, 0, 0, 0);
            sfr[f] = z;
        }

        // logits in log2 domain, mask invalid keys
        float t[4][4];
#pragma unroll
        for (int f = 0; f < 4; ++f)
#pragma unroll
            for (int r = 0; r < 4; ++r) {
                float v = sfr[f][r] * SCALE_L2E;
                if (kbase + f * 16 + lc > Ss - 1) v = -1e30f;
                t[f][r] = v;
            }

        float alpha[4];
#pragma unroll
        for (int r = 0; r < 4; ++r) {
            float m0 = fmaxf(fmaxf(t[0][r], t[1][r]), fmaxf(t[2][r], t[3][r]));
#pragma unroll
            for (int s = 1; s < 16; s <<= 1)
                m0 = fmaxf(m0, __shfl_xor(m0, s, 64));
            float mnew = fmaxf(mrun[r], m0);
            alpha[r] = exp2f(mrun[r] - mnew);
            mrun[r] = mnew;
        }
#pragma unroll
        for (int r = 0; r < 4; ++r) {
            float sum = 0.f;
#pragma unroll
            for (int f = 0; f < 4; ++f) {
                float p = exp2f(t[f][r] - mrun[r]);
                sum += p;
                Pl[wave][(quad * 4 + r) * 80 + f * 16 + lc] = f2b(p);
            }
#pragma unroll
            for (int s = 1; s < 16; s <<= 1)
                sum += __shfl_xor(sum, s, 64);
            lrun[r] = lrun[r] * alpha[r] + sum;
        }
#pragma unroll
        for (int g = 0; g < 4; ++g)
#pragma unroll
            for (int r = 0; r < 4; ++r)
                oacc[g][r] *= alpha[r];

        __syncthreads();  // Vt + Pl writes visible

        // O += P V : P A-frags from LDS, V B-frags from transposed LDS
        short8 pf0 = *(const short8*)(&Pl[wave][lc * 80 + quad * 8]);
        short8 pf1 = *(const short8*)(&Pl[wave][lc * 80 + 32 + quad * 8]);
#pragma unroll
        for (int g = 0; g < 4; ++g) {
            short8 vf0 = *(const short8*)(&Vt[(g * 16 + lc) * 80 + quad * 8]);
            short8 vf1 = *(const short8*)(&Vt[(g * 16 + lc) * 80 + 32 + quad * 8]);
            oacc[g] = __builtin_amdgcn_mfma_f32_16x16x32_bf16(pf0, vf0, oacc[g], 0, 0, 0);
            oacc[g] = __builtin_amdgcn_mfma_f32_16x16x32_bf16(pf1, vf1, oacc[g], 0, 0, 0);
        }
    }

    // epilogue: O /= l, scatter to [b,s,h*64+dh] bf16
#pragma unroll
    for (int r = 0; r < 4; ++r) {
        int q = qbase + quad * 4 + r;
        if (q <= Ss - 1) {
            float inv = 1.f / lrun[r];
            size_t orow = (size_t)(b * Ss + q) * 768 + h * 64;
#pragma unroll
            for (int g = 0; g < 4; ++g)
                outb[orow + g * 16 + lc] = f2b(oacc[g][r] * inv);
        }
    }
}

extern "C" void kernel_launch(void* const* d_in, const int* in_sizes, int n_in,
                              void* d_out, int out_size, void* d_ws, size_t ws_size,
                              hipStream_t stream) {
    const float* x     = (const float*)d_in[0];
    const float* w_qkv = (const float*)d_in[1];
    const float* b_qkv = (const float*)d_in[2];
    const float* w_fc  = (const float*)d_in[3];
    const float* b_fc  = (const float*)d_in[4];

    uint8_t* ws = (uint8_t*)d_ws;
    unsigned short* xb    = (unsigned short*)(ws + 0);           //  28,360,704 B
    unsigned short* wqkvT = (unsigned short*)(ws + 28360704);    //   3,538,944 B
    unsigned short* wfcT  = (unsigned short*)(ws + 31899648);    //   1,179,648 B
    unsigned short* qkv   = (unsigned short*)(ws + 33079296);    //  85,082,112 B
    unsigned short* attn  = (unsigned short*)(ws + 118161408);   //  28,360,704 B
    // total 146,522,112 B

    int n4 = (Mm * Dd) / 4;  // 3,545,088
    cast_f32_bf16<<<(n4 + 255) / 256, 256, 0, stream>>>(x, xb, n4);
    transpose_cast<<<dim3(QKV_N / 32, Dd / 32), dim3(32, 8), 0, stream>>>(w_qkv, wqkvT, Dd, QKV_N);
    transpose_cast<<<dim3(Dd / 32, Dd / 32), dim3(32, 8), 0, stream>>>(w_fc, wfcT, Dd, Dd);

    gemm_tn<QKV_N, true><<<dim3((Mm + 127) / 128, QKV_N / 128), 256, 0, stream>>>(xb, wqkvT, b_qkv, qkv);

    attn_kernel<<<dim3(10, Hh, Bz), 256, 0, stream>>>(qkv, attn);

    gemm_tn<Dd, false><<<dim3((Mm + 127) / 128, Dd / 128), 256, 0, stream>>>(attn, wfcT, b_fc, d_out);
}

// Round 2
// 479.271 us; speedup vs baseline: 1.0994x; 1.0994x over previous
//
#include <hip/hip_runtime.h>
#include <hip/hip_bf16.h>
#include <stdint.h>

typedef __attribute__((ext_vector_type(8))) short short8;   // 8 bf16 = 4 VGPRs
typedef __attribute__((ext_vector_type(4))) float f32x4;    // MFMA C/D frag

typedef __attribute__((address_space(3))) uint8_t lds_u8;
typedef __attribute__((address_space(1))) uint8_t glb_u8;

__device__ __forceinline__ void load_lds_16(const void* g, void* l) {
    __builtin_amdgcn_global_load_lds((glb_u8*)g, (lds_u8*)l, 16, 0, 0);
}

__device__ __forceinline__ unsigned short f2b(float f) {
    __hip_bfloat16 h = __float2bfloat16(f);
    return __builtin_bit_cast(unsigned short, h);
}

constexpr int Bz = 32, Ss = 577, Dd = 768, Hh = 12;
constexpr int Mm = Bz * Ss;          // 18464
constexpr int QKV_N = 3 * Dd;        // 2304
constexpr float SCALE_L2E = 0.125f * 1.4426950408889634f;

// ---------------- cast x -> bf16 ----------------
__global__ void cast_f32_bf16(const float* __restrict__ src,
                              unsigned short* __restrict__ dst, int n4) {
    int i = blockIdx.x * blockDim.x + threadIdx.x;
    if (i >= n4) return;
    float4 v = ((const float4*)src)[i];
    ushort4 o;
    o.x = f2b(v.x); o.y = f2b(v.y); o.z = f2b(v.z); o.w = f2b(v.w);
    ((ushort4*)dst)[i] = o;
}

// ---------------- transpose + cast: src fp32 [R][C] -> dst bf16 [C][R] ----------------
__global__ void transpose_cast(const float* __restrict__ src,
                               unsigned short* __restrict__ dst, int R, int C) {
    __shared__ unsigned short tile[32][33];
    int c0 = blockIdx.x * 32, r0 = blockIdx.y * 32;
    int tx = threadIdx.x, ty = threadIdx.y;  // (32,8)
#pragma unroll
    for (int i = 0; i < 4; ++i)
        tile[ty + i * 8][tx] = f2b(src[(size_t)(r0 + ty + i * 8) * C + c0 + tx]);
    __syncthreads();
#pragma unroll
    for (int i = 0; i < 4; ++i) {
        int rr = ty + i * 8;
        dst[(size_t)(c0 + rr) * R + r0 + tx] = tile[tx][rr];
    }
}

// ---------------- TN GEMM: C[M][N] = A[M][768] * Bt[N][768]^T + bias ----------------
template <int N_, bool OUT_BF16>
__global__ __launch_bounds__(256)
void gemm_tn(const unsigned short* __restrict__ A,
             const unsigned short* __restrict__ Bt,
             const float* __restrict__ bias,
             void* __restrict__ Cout) {
    constexpr int K = 768;
    __shared__ unsigned short Asm[128 * 32];
    __shared__ unsigned short Bsm[128 * 32];

    const int tid = threadIdx.x;
    const int wave = tid >> 6, lane = tid & 63;
    const int quad = lane >> 4, lc = lane & 15;
    const int wm = wave >> 1, wn = wave & 1;
    const int tm = blockIdx.x * 128;
    const int tn = blockIdx.y * 128;

    const int l4 = lane >> 2;
    const int cs = lane & 3;
    const int cx = cs ^ (l4 & 3);

    f32x4 acc[4][4] = {};

    for (int kb = 0; kb < K / 32; ++kb) {
        __syncthreads();
#pragma unroll
        for (int i = 0; i < 2; ++i) {
            int lrow = wave * 32 + i * 16 + l4;
            int arow = tm + lrow; if (arow >= Mm) arow = Mm - 1;
            const unsigned short* ga = A + (size_t)arow * K + kb * 32 + cx * 8;
            load_lds_16(ga, (void*)(Asm + (wave * 32 + i * 16) * 32));
            int brow = tn + lrow;
            const unsigned short* gb = Bt + (size_t)brow * K + kb * 32 + cx * 8;
            load_lds_16(gb, (void*)(Bsm + (wave * 32 + i * 16) * 32));
        }
        __syncthreads();

        short8 af[4], bf[4];
#pragma unroll
        for (int i = 0; i < 4; ++i) {
            int row = wm * 64 + i * 16 + lc;
            int c = quad ^ (row & 3);
            af[i] = *(const short8*)(Asm + row * 32 + c * 8);
            int brow = wn * 64 + i * 16 + lc;
            int cb = quad ^ (brow & 3);
            bf[i] = *(const short8*)(Bsm + brow * 32 + cb * 8);
        }
#pragma unroll
        for (int i = 0; i < 4; ++i)
#pragma unroll
            for (int j = 0; j < 4; ++j)
                acc[i][j] = __builtin_amdgcn_mfma_f32_16x16x32_bf16(af[i], bf[j], acc[i][j], 0, 0, 0);
    }

#pragma unroll
    for (int j = 0; j < 4; ++j) {
        int col = tn + wn * 64 + j * 16 + lc;
        float bv = bias[col];
#pragma unroll
        for (int i = 0; i < 4; ++i) {
#pragma unroll
            for (int r = 0; r < 4; ++r) {
                int row = tm + wm * 64 + i * 16 + quad * 4 + r;
                if (row < Mm) {
                    float v = acc[i][j][r] + bv;
                    if constexpr (OUT_BF16)
                        ((unsigned short*)Cout)[(size_t)row * N_ + col] = f2b(v);
                    else
                        ((float*)Cout)[(size_t)row * N_ + col] = v;
                }
            }
        }
    }
}

// ---------------- flash attention (S^T formulation) ----------------
// grid (5, 12, 32) = (128-query tile, head, batch); 512 threads = 8 waves x 16 queries.
// S^T = K Q^T : keys in registers (row=quad*4+r), queries in lanes (col=lc).
// Key-reduction = 15 in-lane ops + 2 shuffles. O^T = V^T P^T keeps alpha per-lane.

template <bool TAIL>
__device__ __forceinline__ void attn_tile(
    const unsigned short* __restrict__ qkvK,   // + (b*577)*2304 + 768 + h*64
    int kbase,
    const unsigned short* __restrict__ Vtb,    // Vt[buf] : [64 d][80]
    unsigned short* __restrict__ Pqw,          // per-wave [16 q][72 keys]
    const short8& qf0, const short8& qf1,
    int quad, int lc,
    float& mrun, float& lrun, f32x4 (&oacc)[4]) {

    // --- S^T = K Q^T ---
    f32x4 sfr[4];
#pragma unroll
    for (int f = 0; f < 4; ++f) {
        int key = kbase + f * 16 + lc;
        if (TAIL) key = Ss - 1;  // clamp; scores masked below
        const unsigned short* kp = qkvK + (size_t)key * QKV_N;
        short8 k0 = *(const short8*)(kp + quad * 8);
        short8 k1 = *(const short8*)(kp + 32 + quad * 8);
        f32x4 z = {};
        z = __builtin_amdgcn_mfma_f32_16x16x32_bf16(k0, qf0, z, 0, 0, 0);
        z = __builtin_amdgcn_mfma_f32_16x16x32_bf16(k1, qf1, z, 0, 0, 0);
        sfr[f] = z;
    }

    float tv[4][4];
#pragma unroll
    for (int f = 0; f < 4; ++f)
#pragma unroll
        for (int r = 0; r < 4; ++r) {
            float s = sfr[f][r];
            if (TAIL && !(f == 0 && r == 0 && quad == 0)) s = -1e30f;
            tv[f][r] = s;
        }

    // --- running max (raw units; scale folded into exp2 fma) ---
    float m0 = tv[0][0];
#pragma unroll
    for (int f = 0; f < 4; ++f)
#pragma unroll
        for (int r = 0; r < 4; ++r) m0 = fmaxf(m0, tv[f][r]);
    m0 = fmaxf(m0, __shfl_xor(m0, 16, 64));
    m0 = fmaxf(m0, __shfl_xor(m0, 32, 64));
    float mnew = fmaxf(mrun, m0);
    float mc = mnew * SCALE_L2E;
    float alpha = exp2f(__builtin_fmaf(mrun, SCALE_L2E, -mc));
    mrun = mnew;

    // --- p = exp2(s*C - mc), pack to P^T LDS, in-lane partial sum ---
    float sum = 0.f;
#pragma unroll
    for (int f = 0; f < 4; ++f) {
        ushort4 pk;
        float p0 = exp2f(__builtin_fmaf(tv[f][0], SCALE_L2E, -mc));
        float p1 = exp2f(__builtin_fmaf(tv[f][1], SCALE_L2E, -mc));
        float p2 = exp2f(__builtin_fmaf(tv[f][2], SCALE_L2E, -mc));
        float p3 = exp2f(__builtin_fmaf(tv[f][3], SCALE_L2E, -mc));
        sum += (p0 + p1) + (p2 + p3);
        pk.x = f2b(p0); pk.y = f2b(p1); pk.z = f2b(p2); pk.w = f2b(p3);
        *(ushort4*)&Pqw[lc * 72 + f * 16 + quad * 4] = pk;
    }
    sum += __shfl_xor(sum, 16, 64);
    sum += __shfl_xor(sum, 32, 64);
    lrun = lrun * alpha + sum;

#pragma unroll
    for (int g = 0; g < 4; ++g)
#pragma unroll
        for (int r = 0; r < 4; ++r) oacc[g][r] *= alpha;

    __threadfence_block();  // wave-local P^T visibility

    // --- O^T += V^T P^T ---
    short8 pf0 = *(const short8*)&Pqw[lc * 72 + quad * 8];
    short8 pf1 = *(const short8*)&Pqw[lc * 72 + 32 + quad * 8];
#pragma unroll
    for (int g = 0; g < 4; ++g) {
        short8 vf0 = *(const short8*)&Vtb[(g * 16 + lc) * 80 + quad * 8];
        short8 vf1 = *(const short8*)&Vtb[(g * 16 + lc) * 80 + 32 + quad * 8];
        oacc[g] = __builtin_amdgcn_mfma_f32_16x16x32_bf16(vf0, pf0, oacc[g], 0, 0, 0);
        oacc[g] = __builtin_amdgcn_mfma_f32_16x16x32_bf16(vf1, pf1, oacc[g], 0, 0, 0);
    }
}

__global__ __launch_bounds__(512)
void attn_kernel(const unsigned short* __restrict__ qkv,   // [Mm][2304] bf16
                 unsigned short* __restrict__ outb) {      // [Mm][768] bf16
    __shared__ unsigned short Vt[2][64 * 80];   // double-buffered V^T [d][key]
    __shared__ unsigned short Pq[8][16 * 72];   // per-wave P^T-as-[q][key] / O staging

    const int tid = threadIdx.x;
    const int wave = tid >> 6, lane = tid & 63;
    const int quad = lane >> 4, lc = lane & 15;
    const int qt = blockIdx.x, h = blockIdx.y, b = blockIdx.z;

    const unsigned short* qkvB = qkv + (size_t)b * Ss * QKV_N + h * 64;
    const unsigned short* qkvK = qkvB + 768;
    const unsigned short* qkvV = qkvB + 1536;

    const int qbase = qt * 128 + wave * 16;
    int qrow = qbase + lc; if (qrow > Ss - 1) qrow = Ss - 1;
    const unsigned short* qp = qkv + (size_t)(b * Ss + qrow) * QKV_N + h * 64;
    short8 qf0 = *(const short8*)(qp + quad * 8);
    short8 qf1 = *(const short8*)(qp + 32 + quad * 8);

    unsigned short* Pqw = Pq[wave];

    auto stage = [&](int tile, int buf) {
        int key = tile * 64 + lane; if (key > Ss - 1) key = Ss - 1;
        const unsigned short* vp = qkvV + (size_t)key * QKV_N + wave * 8;
        short8 v = *(const short8*)vp;
#pragma unroll
        for (int j = 0; j < 8; ++j)
            Vt[buf][(wave * 8 + j) * 80 + lane] = (unsigned short)v[j];
    };

    float mrun = -1e30f, lrun = 0.f;
    f32x4 oacc[4] = {};

    stage(0, 0);
    for (int kb = 0; kb < 9; ++kb) {
        __syncthreads();              // Vt[kb&1] ready; buf^1 reads from iter kb-1 done
        stage(kb + 1, (kb + 1) & 1);  // prefetch next V tile (tile 9 clamps to key 576)
        attn_tile<false>(qkvK, kb * 64, Vt[kb & 1], Pqw, qf0, qf1,
                         quad, lc, mrun, lrun, oacc);
    }
    __syncthreads();
    attn_tile<true>(qkvK, 576, Vt[1], Pqw, qf0, qf1, quad, lc, mrun, lrun, oacc);

    // --- epilogue: O^T -> LDS transpose -> coalesced bf16 store ---
    float inv = 1.f / lrun;
#pragma unroll
    for (int g = 0; g < 4; ++g) {
        ushort4 ob;
        ob.x = f2b(oacc[g][0] * inv);
        ob.y = f2b(oacc[g][1] * inv);
        ob.z = f2b(oacc[g][2] * inv);
        ob.w = f2b(oacc[g][3] * inv);
        *(ushort4*)&Pqw[lc * 72 + g * 16 + quad * 4] = ob;   // O[q=lc][d contiguous]
    }
    __threadfence_block();
#pragma unroll
    for (int p = 0; p < 2; ++p) {
        int lr = p * 8 + (lane >> 3), ch = lane & 7;
        int q = qbase + lr;
        if (q <= Ss - 1) {
            short8 vv = *(const short8*)&Pqw[lr * 72 + ch * 8];
            *(short8*)(outb + (size_t)(b * Ss + q) * Dd + h * 64 + ch * 8) = vv;
        }
    }
}

extern "C" void kernel_launch(void* const* d_in, const int* in_sizes, int n_in,
                              void* d_out, int out_size, void* d_ws, size_t ws_size,
                              hipStream_t stream) {
    const float* x     = (const float*)d_in[0];
    const float* w_qkv = (const float*)d_in[1];
    const float* b_qkv = (const float*)d_in[2];
    const float* w_fc  = (const float*)d_in[3];
    const float* b_fc  = (const float*)d_in[4];

    uint8_t* ws = (uint8_t*)d_ws;
    unsigned short* xb    = (unsigned short*)(ws + 0);           //  28,360,704 B
    unsigned short* wqkvT = (unsigned short*)(ws + 28360704);    //   3,538,944 B
    unsigned short* wfcT  = (unsigned short*)(ws + 31899648);    //   1,179,648 B
    unsigned short* qkv   = (unsigned short*)(ws + 33079296);    //  85,082,112 B
    unsigned short* attn  = (unsigned short*)(ws + 118161408);   //  28,360,704 B

    int n4 = (Mm * Dd) / 4;
    cast_f32_bf16<<<(n4 + 255) / 256, 256, 0, stream>>>(x, xb, n4);
    transpose_cast<<<dim3(QKV_N / 32, Dd / 32), dim3(32, 8), 0, stream>>>(w_qkv, wqkvT, Dd, QKV_N);
    transpose_cast<<<dim3(Dd / 32, Dd / 32), dim3(32, 8), 0, stream>>>(w_fc, wfcT, Dd, Dd);

    gemm_tn<QKV_N, true><<<dim3((Mm + 127) / 128, QKV_N / 128), 256, 0, stream>>>(xb, wqkvT, b_qkv, qkv);

    attn_kernel<<<dim3(5, Hh, Bz), 512, 0, stream>>>(qkv, attn);

    gemm_tn<Dd, false><<<dim3((Mm + 127) / 128, Dd / 128), 256, 0, stream>>>(attn, wfcT, b_fc, d_out);
}

// Round 4
// 412.685 us; speedup vs baseline: 1.2768x; 1.1613x over previous
//
#include <hip/hip_runtime.h>
#include <hip/hip_bf16.h>
#include <stdint.h>

typedef __attribute__((ext_vector_type(8))) short short8;   // 8 bf16 = 4 VGPRs
typedef __attribute__((ext_vector_type(4))) float f32x4;    // MFMA C/D frag

typedef __attribute__((address_space(3))) uint8_t lds_u8;
typedef __attribute__((address_space(1))) uint8_t glb_u8;

__device__ __forceinline__ void load_lds_16(const void* g, void* l) {
    __builtin_amdgcn_global_load_lds((glb_u8*)g, (lds_u8*)l, 16, 0, 0);
}

__device__ __forceinline__ unsigned short f2b(float f) {
    __hip_bfloat16 h = __float2bfloat16(f);
    return __builtin_bit_cast(unsigned short, h);
}
__device__ __forceinline__ ushort2 f2b2(float a, float b) {
    __hip_bfloat162 h = __float22bfloat162_rn(float2{a, b});
    ushort2 r;
    __builtin_memcpy(&r, &h, sizeof(r));   // __hip_bfloat162 not trivially copyable -> no bit_cast
    return r;
}

constexpr int Bz = 32, Ss = 577, Dd = 768, Hh = 12;
constexpr int Mm = Bz * Ss;          // 18464
constexpr int QKV_N = 3 * Dd;        // 2304
constexpr float SCALE_L2E = 0.125f * 1.4426950408889634f;

// ---------------- cast x -> bf16 ----------------
__global__ void cast_f32_bf16(const float* __restrict__ src,
                              unsigned short* __restrict__ dst, int n4) {
    int i = blockIdx.x * blockDim.x + threadIdx.x;
    if (i >= n4) return;
    float4 v = ((const float4*)src)[i];
    ushort4 o;
    o.x = f2b(v.x); o.y = f2b(v.y); o.z = f2b(v.z); o.w = f2b(v.w);
    ((ushort4*)dst)[i] = o;
}

// ---------------- transpose + cast: src fp32 [R][C] -> dst bf16 [C][R] ----------------
__global__ void transpose_cast(const float* __restrict__ src,
                               unsigned short* __restrict__ dst, int R, int C) {
    __shared__ unsigned short tile[32][33];
    int c0 = blockIdx.x * 32, r0 = blockIdx.y * 32;
    int tx = threadIdx.x, ty = threadIdx.y;  // (32,8)
#pragma unroll
    for (int i = 0; i < 4; ++i)
        tile[ty + i * 8][tx] = f2b(src[(size_t)(r0 + ty + i * 8) * C + c0 + tx]);
    __syncthreads();
#pragma unroll
    for (int i = 0; i < 4; ++i) {
        int rr = ty + i * 8;
        dst[(size_t)(c0 + rr) * R + r0 + tx] = tile[tx][rr];
    }
}

// ---------------- TN GEMM: C[M][N] = A[M][768] * Bt[N][768]^T + bias ----------------
template <int N_, bool OUT_BF16>
__global__ __launch_bounds__(256)
void gemm_tn(const unsigned short* __restrict__ A,
             const unsigned short* __restrict__ Bt,
             const float* __restrict__ bias,
             void* __restrict__ Cout) {
    constexpr int K = 768;
    __shared__ unsigned short Asm[128 * 32];
    __shared__ unsigned short Bsm[128 * 32];

    const int tid = threadIdx.x;
    const int wave = tid >> 6, lane = tid & 63;
    const int quad = lane >> 4, lc = lane & 15;
    const int wm = wave >> 1, wn = wave & 1;
    const int tm = blockIdx.x * 128;
    const int tn = blockIdx.y * 128;

    const int l4 = lane >> 2;
    const int cs = lane & 3;
    const int cx = cs ^ (l4 & 3);

    f32x4 acc[4][4] = {};

    for (int kb = 0; kb < K / 32; ++kb) {
        __syncthreads();
#pragma unroll
        for (int i = 0; i < 2; ++i) {
            int lrow = wave * 32 + i * 16 + l4;
            int arow = tm + lrow; if (arow >= Mm) arow = Mm - 1;
            const unsigned short* ga = A + (size_t)arow * K + kb * 32 + cx * 8;
            load_lds_16(ga, (void*)(Asm + (wave * 32 + i * 16) * 32));
            int brow = tn + lrow;
            const unsigned short* gb = Bt + (size_t)brow * K + kb * 32 + cx * 8;
            load_lds_16(gb, (void*)(Bsm + (wave * 32 + i * 16) * 32));
        }
        __syncthreads();

        short8 af[4], bf[4];
#pragma unroll
        for (int i = 0; i < 4; ++i) {
            int row = wm * 64 + i * 16 + lc;
            int c = quad ^ (row & 3);
            af[i] = *(const short8*)(Asm + row * 32 + c * 8);
            int brow = wn * 64 + i * 16 + lc;
            int cb = quad ^ (brow & 3);
            bf[i] = *(const short8*)(Bsm + brow * 32 + cb * 8);
        }
#pragma unroll
        for (int i = 0; i < 4; ++i)
#pragma unroll
            for (int j = 0; j < 4; ++j)
                acc[i][j] = __builtin_amdgcn_mfma_f32_16x16x32_bf16(af[i], bf[j], acc[i][j], 0, 0, 0);
    }

#pragma unroll
    for (int j = 0; j < 4; ++j) {
        int col = tn + wn * 64 + j * 16 + lc;
        float bv = bias[col];
#pragma unroll
        for (int i = 0; i < 4; ++i) {
#pragma unroll
            for (int r = 0; r < 4; ++r) {
                int row = tm + wm * 64 + i * 16 + quad * 4 + r;
                if (row < Mm) {
                    float v = acc[i][j][r] + bv;
                    if constexpr (OUT_BF16)
                        ((unsigned short*)Cout)[(size_t)row * N_ + col] = f2b(v);
                    else
                        ((float*)Cout)[(size_t)row * N_ + col] = v;
                }
            }
        }
    }
}

// ---------------- flash attention (S^T formulation, K+V prefetched via LDS) ----------------
// grid (5, 12, 32); 512 threads = 8 waves x 16 queries.
// S^T = K Q^T : keys in registers, queries in lanes. O^T = V^T P^T.
// K staged via global_load_lds (8 KB/tile, XOR chunk swizzle), double-buffered.
// V staged via reg->LDS transpose, load issued at tile start, write deferred to tile end.

template <bool TAIL>
__device__ __forceinline__ void attn_tile(
    const unsigned short* __restrict__ Ktile,  // LDS [64 key][64 dh], chunk-swizzled
    const unsigned short* __restrict__ Vtb,    // LDS V^T [64 dh][80]
    unsigned short* __restrict__ Pqw,          // per-wave [16 q][72 keys]
    const short8& qf0, const short8& qf1,
    int quad, int lc,
    float& mrun, float& lrun, f32x4 (&oacc)[4]) {

    // --- S^T = K Q^T ; K frags from swizzled LDS ---
    const int sw = lc & 7;
    f32x4 sfr[4];
#pragma unroll
    for (int f = 0; f < 4; ++f) {
        const unsigned short* kr = Ktile + (f * 16 + lc) * 64;
        short8 k0 = *(const short8*)(kr + (quad ^ sw) * 8);
        short8 k1 = *(const short8*)(kr + ((quad ^ 4) ^ sw) * 8);
        f32x4 z = {};
        z = __builtin_amdgcn_mfma_f32_16x16x32_bf16(k0, qf0, z, 0, 0, 0);
        z = __builtin_amdgcn_mfma_f32_16x16x32_bf16(k1, qf1, z, 0, 0, 0);
        sfr[f] = z;
    }

    float tv[4][4];
#pragma unroll
    for (int f = 0; f < 4; ++f)
#pragma unroll
        for (int r = 0; r < 4; ++r) {
            float s = sfr[f][r];
            if (TAIL && !(f == 0 && r == 0 && quad == 0)) s = -1e30f;
            tv[f][r] = s;
        }

    // --- running max (raw units; scale folded into exp2 fma) ---
    float m0 = tv[0][0];
#pragma unroll
    for (int f = 0; f < 4; ++f)
#pragma unroll
        for (int r = 0; r < 4; ++r) m0 = fmaxf(m0, tv[f][r]);
    m0 = fmaxf(m0, __shfl_xor(m0, 16, 64));
    m0 = fmaxf(m0, __shfl_xor(m0, 32, 64));
    float mnew = fmaxf(mrun, m0);
    float mc = mnew * SCALE_L2E;
    float alpha = exp2f(__builtin_fmaf(mrun, SCALE_L2E, -mc));
    mrun = mnew;

    // --- p = exp2(s*C - mc), pack to P^T LDS, in-lane partial sum ---
    float sum = 0.f;
#pragma unroll
    for (int f = 0; f < 4; ++f) {
        float p0 = exp2f(__builtin_fmaf(tv[f][0], SCALE_L2E, -mc));
        float p1 = exp2f(__builtin_fmaf(tv[f][1], SCALE_L2E, -mc));
        float p2 = exp2f(__builtin_fmaf(tv[f][2], SCALE_L2E, -mc));
        float p3 = exp2f(__builtin_fmaf(tv[f][3], SCALE_L2E, -mc));
        sum += (p0 + p1) + (p2 + p3);
        ushort2 lo = f2b2(p0, p1), hi = f2b2(p2, p3);
        ushort4 pk = {lo.x, lo.y, hi.x, hi.y};
        *(ushort4*)&Pqw[lc * 72 + f * 16 + quad * 4] = pk;
    }
    sum += __shfl_xor(sum, 16, 64);
    sum += __shfl_xor(sum, 32, 64);
    lrun = lrun * alpha + sum;

#pragma unroll
    for (int g = 0; g < 4; ++g)
#pragma unroll
        for (int r = 0; r < 4; ++r) oacc[g][r] *= alpha;

    __threadfence_block();  // wave-local P^T visibility

    // --- O^T += V^T P^T ---
    short8 pf0 = *(const short8*)&Pqw[lc * 72 + quad * 8];
    short8 pf1 = *(const short8*)&Pqw[lc * 72 + 32 + quad * 8];
#pragma unroll
    for (int g = 0; g < 4; ++g) {
        short8 vf0 = *(const short8*)&Vtb[(g * 16 + lc) * 80 + quad * 8];
        short8 vf1 = *(const short8*)&Vtb[(g * 16 + lc) * 80 + 32 + quad * 8];
        oacc[g] = __builtin_amdgcn_mfma_f32_16x16x32_bf16(vf0, pf0, oacc[g], 0, 0, 0);
        oacc[g] = __builtin_amdgcn_mfma_f32_16x16x32_bf16(vf1, pf1, oacc[g], 0, 0, 0);
    }
}

__global__ __launch_bounds__(512)
void attn_kernel(const unsigned short* __restrict__ qkv,   // [Mm][2304] bf16
                 unsigned short* __restrict__ outb) {      // [Mm][768] bf16
    __shared__ unsigned short Kt[2][64 * 64];   // dbuf K [key][dh], chunk-swizzled
    __shared__ unsigned short Vt[2][64 * 80];   // dbuf V^T [dh][key]
    __shared__ unsigned short Pq[8][16 * 72];   // per-wave P^T / O staging

    const int tid = threadIdx.x;
    const int wave = tid >> 6, lane = tid & 63;
    const int quad = lane >> 4, lc = lane & 15;
    const int qt = blockIdx.x, h = blockIdx.y, b = blockIdx.z;

    const unsigned short* qkvK = qkv + (size_t)b * Ss * QKV_N + h * 64 + 768;
    const unsigned short* qkvV = qkvK + 768;

    // K staging map: wave slab = 8 keys; lane -> (row = lane>>3, chunk c' = lane&7)
    // global chunk c = c' ^ row  (keys 8-aligned so key&7 == row)
    const int krow = lane >> 3;
    const int gch = (lane & 7) ^ krow;

    const int qbase = qt * 128 + wave * 16;
    int qrow = qbase + lc; if (qrow > Ss - 1) qrow = Ss - 1;
    const unsigned short* qp = qkv + (size_t)(b * Ss + qrow) * QKV_N + h * 64;
    short8 qf0 = *(const short8*)(qp + quad * 8);
    short8 qf1 = *(const short8*)(qp + 32 + quad * 8);

    unsigned short* Pqw = Pq[wave];

    auto stage_K = [&](int tile, int buf) {
        int key = tile * 64 + wave * 8 + krow; if (key > Ss - 1) key = Ss - 1;
        const unsigned short* gp = qkvK + (size_t)key * QKV_N + gch * 8;
        load_lds_16(gp, (void*)&Kt[buf][wave * 512]);
    };
    auto load_V = [&](int tile) -> short8 {
        int key = tile * 64 + lane; if (key > Ss - 1) key = Ss - 1;
        return *(const short8*)(qkvV + (size_t)key * QKV_N + wave * 8);
    };
    auto write_V = [&](short8 v, int buf) {
#pragma unroll
        for (int j = 0; j < 8; ++j)
            Vt[buf][(wave * 8 + j) * 80 + lane] = (unsigned short)v[j];
    };

    float mrun = -1e30f, lrun = 0.f;
    f32x4 oacc[4] = {};

    stage_K(0, 0);
    write_V(load_V(0), 0);
    __syncthreads();   // drains K-lds (compiler vmcnt(0) before barrier)

    for (int kb = 0; kb < 9; ++kb) {
        const int buf = kb & 1;
        stage_K(kb + 1, buf ^ 1);          // async global->LDS, no reg round-trip
        short8 vreg = load_V(kb + 1);      // async into regs, consumed after compute
        attn_tile<false>(Kt[buf], Vt[buf], Pqw, qf0, qf1, quad, lc, mrun, lrun, oacc);
        write_V(vreg, buf ^ 1);            // vmcnt wait lands here, ~late
        __syncthreads();
    }
    attn_tile<true>(Kt[1], Vt[1], Pqw, qf0, qf1, quad, lc, mrun, lrun, oacc);

    // --- epilogue: O^T -> LDS transpose -> coalesced bf16 store ---
    float inv = 1.f / lrun;
#pragma unroll
    for (int g = 0; g < 4; ++g) {
        ushort2 lo = f2b2(oacc[g][0] * inv, oacc[g][1] * inv);
        ushort2 hi = f2b2(oacc[g][2] * inv, oacc[g][3] * inv);
        ushort4 ob = {lo.x, lo.y, hi.x, hi.y};
        *(ushort4*)&Pqw[lc * 72 + g * 16 + quad * 4] = ob;   // O[q=lc][d contiguous]
    }
    __threadfence_block();
#pragma unroll
    for (int p = 0; p < 2; ++p) {
        int lr = p * 8 + (lane >> 3), ch = lane & 7;
        int q = qbase + lr;
        if (q <= Ss - 1) {
            short8 vv = *(const short8*)&Pqw[lr * 72 + ch * 8];
            *(short8*)(outb + (size_t)(b * Ss + q) * Dd + h * 64 + ch * 8) = vv;
        }
    }
}

extern "C" void kernel_launch(void* const* d_in, const int* in_sizes, int n_in,
                              void* d_out, int out_size, void* d_ws, size_t ws_size,
                              hipStream_t stream) {
    const float* x     = (const float*)d_in[0];
    const float* w_qkv = (const float*)d_in[1];
    const float* b_qkv = (const float*)d_in[2];
    const float* w_fc  = (const float*)d_in[3];
    const float* b_fc  = (const float*)d_in[4];

    uint8_t* ws = (uint8_t*)d_ws;
    unsigned short* xb    = (unsigned short*)(ws + 0);           //  28,360,704 B
    unsigned short* wqkvT = (unsigned short*)(ws + 28360704);    //   3,538,944 B
    unsigned short* wfcT  = (unsigned short*)(ws + 31899648);    //   1,179,648 B
    unsigned short* qkv   = (unsigned short*)(ws + 33079296);    //  85,082,112 B
    unsigned short* attn  = (unsigned short*)(ws + 118161408);   //  28,360,704 B

    int n4 = (Mm * Dd) / 4;
    cast_f32_bf16<<<(n4 + 255) / 256, 256, 0, stream>>>(x, xb, n4);
    transpose_cast<<<dim3(QKV_N / 32, Dd / 32), dim3(32, 8), 0, stream>>>(w_qkv, wqkvT, Dd, QKV_N);
    transpose_cast<<<dim3(Dd / 32, Dd / 32), dim3(32, 8), 0, stream>>>(w_fc, wfcT, Dd, Dd);

    gemm_tn<QKV_N, true><<<dim3((Mm + 127) / 128, QKV_N / 128), 256, 0, stream>>>(xb, wqkvT, b_qkv, qkv);

    attn_kernel<<<dim3(5, Hh, Bz), 512, 0, stream>>>(qkv, attn);

    gemm_tn<Dd, false><<<dim3((Mm + 127) / 128, Dd / 128), 256, 0, stream>>>(attn, wfcT, b_fc, d_out);
}

// Round 6
// 368.861 us; speedup vs baseline: 1.4285x; 1.1188x over previous
//
#include <hip/hip_runtime.h>
#include <hip/hip_bf16.h>
#include <stdint.h>

typedef __attribute__((ext_vector_type(8))) short short8;   // 8 bf16 = 4 VGPRs
typedef __attribute__((ext_vector_type(4))) float f32x4;    // MFMA C/D frag

typedef __attribute__((address_space(3))) uint8_t lds_u8;
typedef __attribute__((address_space(1))) uint8_t glb_u8;

__device__ __forceinline__ void load_lds_16(const void* g, void* l) {
    __builtin_amdgcn_global_load_lds((glb_u8*)g, (lds_u8*)l, 16, 0, 0);
}

__device__ __forceinline__ unsigned short f2b(float f) {
    __hip_bfloat16 h = __float2bfloat16(f);
    return __builtin_bit_cast(unsigned short, h);
}
__device__ __forceinline__ ushort2 f2b2(float a, float b) {
    __hip_bfloat162 h = __float22bfloat162_rn(float2{a, b});
    ushort2 r;
    __builtin_memcpy(&r, &h, sizeof(r));   // __hip_bfloat162 not trivially copyable -> no bit_cast
    return r;
}

constexpr int Bz = 32, Ss = 577, Dd = 768, Hh = 12;
constexpr int Mm = Bz * Ss;          // 18464
constexpr int QKV_N = 3 * Dd;        // 2304
constexpr float SCALE_L2E = 0.125f * 1.4426950408889634f;

// ---------------- cast x -> bf16 ----------------
__global__ void cast_f32_bf16(const float* __restrict__ src,
                              unsigned short* __restrict__ dst, int n4) {
    int i = blockIdx.x * blockDim.x + threadIdx.x;
    if (i >= n4) return;
    float4 v = ((const float4*)src)[i];
    ushort4 o;
    o.x = f2b(v.x); o.y = f2b(v.y); o.z = f2b(v.z); o.w = f2b(v.w);
    ((ushort4*)dst)[i] = o;
}

// ---------------- transpose + cast: src fp32 [R][C] -> dst bf16 [C][R] ----------------
__global__ void transpose_cast(const float* __restrict__ src,
                               unsigned short* __restrict__ dst, int R, int C) {
    __shared__ unsigned short tile[32][33];
    int c0 = blockIdx.x * 32, r0 = blockIdx.y * 32;
    int tx = threadIdx.x, ty = threadIdx.y;  // (32,8)
#pragma unroll
    for (int i = 0; i < 4; ++i)
        tile[ty + i * 8][tx] = f2b(src[(size_t)(r0 + ty + i * 8) * C + c0 + tx]);
    __syncthreads();
#pragma unroll
    for (int i = 0; i < 4; ++i) {
        int rr = ty + i * 8;
        dst[(size_t)(c0 + rr) * R + r0 + tx] = tile[tx][rr];
    }
}

// ---------------- TN GEMM: C[M][N] = A[M][768] * Bt[N][768]^T + bias ----------------
// 128x128 tile, BK=32, 4 waves. Double-buffered global_load_lds staging with
// next-tile prefetch issued BEFORE compute. LDS buffer selected via integer
// offset (NO local pointer arrays to __shared__ -- gfx950 rejects the
// addrspacecast static initializer).
template <int N_, bool OUT_BF16>
__global__ __launch_bounds__(256)
void gemm_tn(const unsigned short* __restrict__ A,
             const unsigned short* __restrict__ Bt,
             const float* __restrict__ bias,
             void* __restrict__ Cout) {
    constexpr int K = 768;
    constexpr int KB = K / 32;   // 24
    __shared__ __align__(16) uint8_t smem[32768];
    // layout: A0 @0, A1 @8192, B0 @16384, B1 @24576

    const int tid = threadIdx.x;
    const int wave = tid >> 6, lane = tid & 63;
    const int quad = lane >> 4, lc = lane & 15;
    const int wm = wave >> 1, wn = wave & 1;
    const int tm = blockIdx.x * 128;
    const int tn = blockIdx.y * 128;

    const int l4 = lane >> 2;
    const int cx = (lane & 3) ^ (l4 & 3);   // XOR chunk swizzle

    auto stage = [&](int kb, int buf) {
        uint8_t* Ab = smem + buf * 8192;
        uint8_t* Bb = smem + 16384 + buf * 8192;
#pragma unroll
        for (int i = 0; i < 2; ++i) {
            int lrow = wave * 32 + i * 16 + l4;
            int arow = tm + lrow; if (arow >= Mm) arow = Mm - 1;
            load_lds_16(A + (size_t)arow * K + kb * 32 + cx * 8,
                        (void*)(Ab + (wave * 32 + i * 16) * 64));
            int brow = tn + lrow;
            load_lds_16(Bt + (size_t)brow * K + kb * 32 + cx * 8,
                        (void*)(Bb + (wave * 32 + i * 16) * 64));
        }
    };

    f32x4 acc[4][4] = {};
    stage(0, 0);
    __syncthreads();

    for (int kb = 0; kb < KB; ++kb) {
        const int buf = kb & 1;
        if (kb + 1 < KB) stage(kb + 1, buf ^ 1);   // prefetch next tile (async)

        const unsigned short* Ar = (const unsigned short*)(smem + buf * 8192);
        const unsigned short* Br = (const unsigned short*)(smem + 16384 + buf * 8192);
        short8 af[4], bf[4];
#pragma unroll
        for (int i = 0; i < 4; ++i) {
            int row = wm * 64 + i * 16 + lc;
            int c = quad ^ (row & 3);
            af[i] = *(const short8*)(Ar + row * 32 + c * 8);
            int brow = wn * 64 + i * 16 + lc;
            int cb = quad ^ (brow & 3);
            bf[i] = *(const short8*)(Br + brow * 32 + cb * 8);
        }
#pragma unroll
        for (int i = 0; i < 4; ++i)
#pragma unroll
            for (int j = 0; j < 4; ++j)
                acc[i][j] = __builtin_amdgcn_mfma_f32_16x16x32_bf16(af[i], bf[j], acc[i][j], 0, 0, 0);
        __syncthreads();   // reads of buf done + prefetch into buf^1 drained
    }

    // ---- epilogue: wave-private LDS transpose, coalesced vector stores ----
    float bv[4];
#pragma unroll
    for (int j = 0; j < 4; ++j) bv[j] = bias[tn + wn * 64 + j * 16 + lc];

    float* ep = (float*)smem + wave * (16 * 68);   // 16 rows x 68 f32 (4352 B/wave)
    const int erow = lane >> 2, ec = (lane & 3) * 16;
#pragma unroll
    for (int i = 0; i < 4; ++i) {
#pragma unroll
        for (int j = 0; j < 4; ++j)
#pragma unroll
            for (int r = 0; r < 4; ++r)
                ep[(quad * 4 + r) * 68 + j * 16 + lc] = acc[i][j][r] + bv[j];
        __threadfence_block();   // wave-local LDS ordering (DS ops in-order per wave)
        int grow = tm + wm * 64 + i * 16 + erow;
        if (grow < Mm) {
            float4 c0 = *(float4*)&ep[erow * 68 + ec + 0];
            float4 c1 = *(float4*)&ep[erow * 68 + ec + 4];
            float4 c2 = *(float4*)&ep[erow * 68 + ec + 8];
            float4 c3 = *(float4*)&ep[erow * 68 + ec + 12];
            int gcol = tn + wn * 64 + ec;
            if constexpr (OUT_BF16) {
                unsigned short o[16];
                *(ushort2*)&o[0]  = f2b2(c0.x, c0.y);
                *(ushort2*)&o[2]  = f2b2(c0.z, c0.w);
                *(ushort2*)&o[4]  = f2b2(c1.x, c1.y);
                *(ushort2*)&o[6]  = f2b2(c1.z, c1.w);
                *(ushort2*)&o[8]  = f2b2(c2.x, c2.y);
                *(ushort2*)&o[10] = f2b2(c2.z, c2.w);
                *(ushort2*)&o[12] = f2b2(c3.x, c3.y);
                *(ushort2*)&o[14] = f2b2(c3.z, c3.w);
                unsigned short* op = (unsigned short*)Cout + (size_t)grow * N_ + gcol;
                *(short8*)(op + 0) = *(short8*)&o[0];
                *(short8*)(op + 8) = *(short8*)&o[8];
            } else {
                float* op = (float*)Cout + (size_t)grow * N_ + gcol;
                *(float4*)(op + 0)  = c0;
                *(float4*)(op + 4)  = c1;
                *(float4*)(op + 8)  = c2;
                *(float4*)(op + 12) = c3;
            }
        }
        __threadfence_block();   // reads of this slab done before next i overwrites
    }
}

// ---------------- flash attention (S^T formulation, K+V prefetched via LDS) ----------------
// grid (5, 12, 32); 512 threads = 8 waves x 16 queries.
// S^T = K Q^T : keys in registers, queries in lanes. O^T = V^T P^T.

template <bool TAIL>
__device__ __forceinline__ void attn_tile(
    const unsigned short* __restrict__ Ktile,  // LDS [64 key][64 dh], chunk-swizzled
    const unsigned short* __restrict__ Vtb,    // LDS V^T [64 dh][80]
    unsigned short* __restrict__ Pqw,          // per-wave [16 q][72 keys]
    const short8& qf0, const short8& qf1,
    int quad, int lc,
    float& mrun, float& lrun, f32x4 (&oacc)[4]) {

    // --- S^T = K Q^T ; K frags from swizzled LDS ---
    const int sw = lc & 7;
    f32x4 sfr[4];
#pragma unroll
    for (int f = 0; f < 4; ++f) {
        const unsigned short* kr = Ktile + (f * 16 + lc) * 64;
        short8 k0 = *(const short8*)(kr + (quad ^ sw) * 8);
        short8 k1 = *(const short8*)(kr + ((quad ^ 4) ^ sw) * 8);
        f32x4 z = {};
        z = __builtin_amdgcn_mfma_f32_16x16x32_bf16(k0, qf0, z, 0, 0, 0);
        z = __builtin_amdgcn_mfma_f32_16x16x32_bf16(k1, qf1, z, 0, 0, 0);
        sfr[f] = z;
    }

    float tv[4][4];
#pragma unroll
    for (int f = 0; f < 4; ++f)
#pragma unroll
        for (int r = 0; r < 4; ++r) {
            float s = sfr[f][r];
            if (TAIL && !(f == 0 && r == 0 && quad == 0)) s = -1e30f;
            tv[f][r] = s;
        }

    // --- running max (raw units; scale folded into exp2 fma) ---
    float m0 = tv[0][0];
#pragma unroll
    for (int f = 0; f < 4; ++f)
#pragma unroll
        for (int r = 0; r < 4; ++r) m0 = fmaxf(m0, tv[f][r]);
    m0 = fmaxf(m0, __shfl_xor(m0, 16, 64));
    m0 = fmaxf(m0, __shfl_xor(m0, 32, 64));
    float mnew = fmaxf(mrun, m0);
    float mc = mnew * SCALE_L2E;
    float alpha = exp2f(__builtin_fmaf(mrun, SCALE_L2E, -mc));
    mrun = mnew;

    // --- p = exp2(s*C - mc), pack to P^T LDS, in-lane partial sum ---
    float sum = 0.f;
#pragma unroll
    for (int f = 0; f < 4; ++f) {
        float p0 = exp2f(__builtin_fmaf(tv[f][0], SCALE_L2E, -mc));
        float p1 = exp2f(__builtin_fmaf(tv[f][1], SCALE_L2E, -mc));
        float p2 = exp2f(__builtin_fmaf(tv[f][2], SCALE_L2E, -mc));
        float p3 = exp2f(__builtin_fmaf(tv[f][3], SCALE_L2E, -mc));
        sum += (p0 + p1) + (p2 + p3);
        ushort2 lo = f2b2(p0, p1), hi = f2b2(p2, p3);
        ushort4 pk = {lo.x, lo.y, hi.x, hi.y};
        *(ushort4*)&Pqw[lc * 72 + f * 16 + quad * 4] = pk;
    }
    sum += __shfl_xor(sum, 16, 64);
    sum += __shfl_xor(sum, 32, 64);
    lrun = lrun * alpha + sum;

#pragma unroll
    for (int g = 0; g < 4; ++g)
#pragma unroll
        for (int r = 0; r < 4; ++r) oacc[g][r] *= alpha;

    __threadfence_block();  // wave-local P^T visibility

    // --- O^T += V^T P^T ---
    short8 pf0 = *(const short8*)&Pqw[lc * 72 + quad * 8];
    short8 pf1 = *(const short8*)&Pqw[lc * 72 + 32 + quad * 8];
#pragma unroll
    for (int g = 0; g < 4; ++g) {
        short8 vf0 = *(const short8*)&Vtb[(g * 16 + lc) * 80 + quad * 8];
        short8 vf1 = *(const short8*)&Vtb[(g * 16 + lc) * 80 + 32 + quad * 8];
        oacc[g] = __builtin_amdgcn_mfma_f32_16x16x32_bf16(vf0, pf0, oacc[g], 0, 0, 0);
        oacc[g] = __builtin_amdgcn_mfma_f32_16x16x32_bf16(vf1, pf1, oacc[g], 0, 0, 0);
    }
}

__global__ __launch_bounds__(512)
void attn_kernel(const unsigned short* __restrict__ qkv,   // [Mm][2304] bf16
                 unsigned short* __restrict__ outb) {      // [Mm][768] bf16
    __shared__ unsigned short Kt[2][64 * 64];   // dbuf K [key][dh], chunk-swizzled
    __shared__ unsigned short Vt[2][64 * 80];   // dbuf V^T [dh][key]
    __shared__ unsigned short Pq[8][16 * 72];   // per-wave P^T / O staging

    const int tid = threadIdx.x;
    const int wave = tid >> 6, lane = tid & 63;
    const int quad = lane >> 4, lc = lane & 15;
    const int qt = blockIdx.x, h = blockIdx.y, b = blockIdx.z;

    const unsigned short* qkvK = qkv + (size_t)b * Ss * QKV_N + h * 64 + 768;
    const unsigned short* qkvV = qkvK + 768;

    const int krow = lane >> 3;
    const int gch = (lane & 7) ^ krow;

    const int qbase = qt * 128 + wave * 16;
    int qrow = qbase + lc; if (qrow > Ss - 1) qrow = Ss - 1;
    const unsigned short* qp = qkv + (size_t)(b * Ss + qrow) * QKV_N + h * 64;
    short8 qf0 = *(const short8*)(qp + quad * 8);
    short8 qf1 = *(const short8*)(qp + 32 + quad * 8);

    unsigned short* Pqw = Pq[wave];

    auto stage_K = [&](int tile, int buf) {
        int key = tile * 64 + wave * 8 + krow; if (key > Ss - 1) key = Ss - 1;
        const unsigned short* gp = qkvK + (size_t)key * QKV_N + gch * 8;
        load_lds_16(gp, (void*)&Kt[buf][wave * 512]);
    };
    auto load_V = [&](int tile) -> short8 {
        int key = tile * 64 + lane; if (key > Ss - 1) key = Ss - 1;
        return *(const short8*)(qkvV + (size_t)key * QKV_N + wave * 8);
    };
    auto write_V = [&](short8 v, int buf) {
#pragma unroll
        for (int j = 0; j < 8; ++j)
            Vt[buf][(wave * 8 + j) * 80 + lane] = (unsigned short)v[j];
    };

    float mrun = -1e30f, lrun = 0.f;
    f32x4 oacc[4] = {};

    stage_K(0, 0);
    write_V(load_V(0), 0);
    __syncthreads();

    for (int kb = 0; kb < 9; ++kb) {
        const int buf = kb & 1;
        stage_K(kb + 1, buf ^ 1);
        short8 vreg = load_V(kb + 1);
        attn_tile<false>(Kt[buf], Vt[buf], Pqw, qf0, qf1, quad, lc, mrun, lrun, oacc);
        write_V(vreg, buf ^ 1);
        __syncthreads();
    }
    attn_tile<true>(Kt[1], Vt[1], Pqw, qf0, qf1, quad, lc, mrun, lrun, oacc);

    // --- epilogue: O^T -> LDS transpose -> coalesced bf16 store ---
    float inv = 1.f / lrun;
#pragma unroll
    for (int g = 0; g < 4; ++g) {
        ushort2 lo = f2b2(oacc[g][0] * inv, oacc[g][1] * inv);
        ushort2 hi = f2b2(oacc[g][2] * inv, oacc[g][3] * inv);
        ushort4 ob = {lo.x, lo.y, hi.x, hi.y};
        *(ushort4*)&Pqw[lc * 72 + g * 16 + quad * 4] = ob;
    }
    __threadfence_block();
#pragma unroll
    for (int p = 0; p < 2; ++p) {
        int lr = p * 8 + (lane >> 3), ch = lane & 7;
        int q = qbase + lr;
        if (q <= Ss - 1) {
            short8 vv = *(const short8*)&Pqw[lr * 72 + ch * 8];
            *(short8*)(outb + (size_t)(b * Ss + q) * Dd + h * 64 + ch * 8) = vv;
        }
    }
}

extern "C" void kernel_launch(void* const* d_in, const int* in_sizes, int n_in,
                              void* d_out, int out_size, void* d_ws, size_t ws_size,
                              hipStream_t stream) {
    const float* x     = (const float*)d_in[0];
    const float* w_qkv = (const float*)d_in[1];
    const float* b_qkv = (const float*)d_in[2];
    const float* w_fc  = (const float*)d_in[3];
    const float* b_fc  = (const float*)d_in[4];

    uint8_t* ws = (uint8_t*)d_ws;
    unsigned short* xb    = (unsigned short*)(ws + 0);           //  28,360,704 B
    unsigned short* wqkvT = (unsigned short*)(ws + 28360704);    //   3,538,944 B
    unsigned short* wfcT  = (unsigned short*)(ws + 31899648);    //   1,179,648 B
    unsigned short* qkv   = (unsigned short*)(ws + 33079296);    //  85,082,112 B
    unsigned short* attn  = (unsigned short*)(ws + 118161408);   //  28,360,704 B

    int n4 = (Mm * Dd) / 4;
    cast_f32_bf16<<<(n4 + 255) / 256, 256, 0, stream>>>(x, xb, n4);
    transpose_cast<<<dim3(QKV_N / 32, Dd / 32), dim3(32, 8), 0, stream>>>(w_qkv, wqkvT, Dd, QKV_N);
    transpose_cast<<<dim3(Dd / 32, Dd / 32), dim3(32, 8), 0, stream>>>(w_fc, wfcT, Dd, Dd);

    gemm_tn<QKV_N, true><<<dim3((Mm + 127) / 128, QKV_N / 128), 256, 0, stream>>>(xb, wqkvT, b_qkv, qkv);

    attn_kernel<<<dim3(5, Hh, Bz), 512, 0, stream>>>(qkv, attn);

    gemm_tn<Dd, false><<<dim3((Mm + 127) / 128, Dd / 128), 256, 0, stream>>>(attn, wfcT, b_fc, d_out);
}